// Round 6
// baseline (328.660 us; speedup 1.0000x reference)
//
#include <hip/hip_runtime.h>
#include <hip/hip_bf16.h>

#define N_NODES 32768
#define E_EDGES 524288
#define HIDDIM 128
#define FDIM 512
#define DFF 2048
#define LN_EPS 1e-5f
#define SLOPE 0.2f
#define CAP 64          // CSR slot capacity per dst (Poisson(16): P(>64) ~ 1e-19)

typedef __bf16 bf16_t;
typedef __bf16 bf16x8 __attribute__((ext_vector_type(8)));
typedef float f32x4 __attribute__((ext_vector_type(4)));
typedef float f32x2 __attribute__((ext_vector_type(2)));

#define GLD_LDS16(gp, lp) __builtin_amdgcn_global_load_lds( \
    (const __attribute__((address_space(1))) unsigned int*)(gp), \
    (__attribute__((address_space(3))) unsigned int*)(lp), 16, 0, 0)

// ---------- fp8 e4m3 codec (HW cvt when available) ----------
__device__ inline unsigned char f32_to_e4m3(float v) {
#if __has_builtin(__builtin_amdgcn_cvt_pk_fp8_f32)
    return (unsigned char)(__builtin_amdgcn_cvt_pk_fp8_f32(v, v, 0, false) & 0xff);
#else
    unsigned bits = __float_as_uint(v);
    unsigned sign = (bits >> 24) & 0x80;
    float av = fabsf(v);
    if (av >= 448.f) return (unsigned char)(sign | 0x7E);
    int e = (int)((bits >> 23) & 0xFF) - 127;
    if (e < -6) { int n = (int)rintf(av * 512.f); return (unsigned char)(sign | n); }
    float ulp = exp2f((float)(e - 3));
    int n = (int)rintf(av / ulp);
    if (n == 16) { e += 1; n = 8; }
    return (unsigned char)(sign | ((e + 7) << 3) | (n - 8));
#endif
}
template<bool HI>
__device__ inline f32x2 e4m3x2_to_f32(unsigned u) {
#if __has_builtin(__builtin_amdgcn_cvt_pk_f32_fp8)
    return __builtin_amdgcn_cvt_pk_f32_fp8(u, HI);
#else
    f32x2 r;
    unsigned b0 = HI ? ((u >> 16) & 0xff) : (u & 0xff);
    unsigned b1 = HI ? ((u >> 24) & 0xff) : ((u >> 8) & 0xff);
    unsigned bs[2] = {b0, b1};
    for (int i = 0; i < 2; ++i) {
        unsigned b = bs[i];
        float s = (b & 0x80) ? -1.f : 1.f;
        int e = (b >> 3) & 15, m = b & 7;
        float v = e ? (8 + m) * exp2f((float)(e - 10)) : m * exp2f(-9.f);
        r[i] = s * v;
    }
    return r;
#endif
}

// ============ prep: h->bf16, all weight k8-packs, ce — one dispatch ============
__device__ inline void pack_range(const float* __restrict__ B, bf16_t* __restrict__ out,
                                  int id, int N) {
    const int g = id / N, n = id % N;
    union { bf16_t b[8]; uint4 u; } pk;
#pragma unroll
    for (int j = 0; j < 8; ++j) pk.b[j] = (bf16_t)B[(size_t)(g * 8 + j) * N + n];
    *(uint4*)(out + (size_t)id * 8) = pk.u;
}

__global__ __launch_bounds__(256) void prep_kernel(const float* __restrict__ h, bf16_t* __restrict__ hb,
                                                   const float* __restrict__ W_fc, bf16_t* __restrict__ Wfc_p,
                                                   const float* __restrict__ W_res, bf16_t* __restrict__ Wres_p,
                                                   const float* __restrict__ W_mha, bf16_t* __restrict__ Wmha_p,
                                                   const float* __restrict__ W1, bf16_t* __restrict__ W1_p,
                                                   const float* __restrict__ W2, bf16_t* __restrict__ W2_p,
                                                   const float* __restrict__ W_fe, const float* __restrict__ attn_e,
                                                   float* __restrict__ ce) {
    int bid = blockIdx.x;
    const int tid = threadIdx.x;
    if (bid < 4096) {                       // h fp32 -> bf16 (4 elems/thread)
        const int id = bid * 256 + tid;
        const float4 v = ((const float4*)h)[id];
        union { bf16_t b[4]; uint2 u; } pk;
        pk.b[0] = (bf16_t)v.x; pk.b[1] = (bf16_t)v.y; pk.b[2] = (bf16_t)v.z; pk.b[3] = (bf16_t)v.w;
        *(uint2*)(hb + (size_t)id * 4) = pk.u;
        return;
    }
    bid -= 4096;
    if (bid < 32)  { pack_range(W_fc,  Wfc_p,  bid * 256 + tid, 512);  return; }
    bid -= 32;
    if (bid < 32)  { pack_range(W_res, Wres_p, bid * 256 + tid, 512);  return; }
    bid -= 32;
    if (bid < 32)  { pack_range(W_mha, Wmha_p, bid * 256 + tid, 128);  return; }
    bid -= 32;
    if (bid < 128) { pack_range(W1,    W1_p,   bid * 256 + tid, 2048); return; }
    bid -= 128;
    if (bid < 128) { pack_range(W2,    W2_p,   bid * 256 + tid, 128);  return; }
    // ce
    if (tid < 128) {
        const float4 w = ((const float4*)W_fe)[tid];
        const float4 a = ((const float4*)attn_e)[tid];
        float p = w.x * a.x + w.y * a.y + w.z * a.z + w.w * a.w;
        for (int off = 16; off; off >>= 1) p += __shfl_down(p, off, 32);
        if ((tid & 31) == 0) ce[tid >> 5] = p;
    }
}

// ============ generic bf16 MFMA GEMM (used for res): C bf16 = A @ Bp ============
__global__ __launch_bounds__(256) void gemm_mfma(const bf16_t* __restrict__ A,
                                                 const bf16_t* __restrict__ Bp,
                                                 bf16_t* __restrict__ C,
                                                 int M, int N, int K) {
    __shared__ __align__(16) bf16_t lA[4096];
    __shared__ __align__(16) bf16_t lB[4096];
    const int tid = threadIdx.x;
    const int lane = tid & 63;
    const int wave = tid >> 6;
    const int wm = (wave >> 1) * 64, wn = (wave & 1) * 64;
    const int row0 = blockIdx.y * 128, col0 = blockIdx.x * 128;
    const int ko = lane >> 4;
    const int rl = lane & 15;
    f32x4 acc[4][4] = {};
    const int c0 = tid, c1 = tid + 256;
    const int g0 = c0 >> 7, m0 = c0 & 127;
    const int g1 = c1 >> 7, m1 = c1 & 127;
    for (int k0 = 0; k0 < K; k0 += 32) {
        __syncthreads();
        GLD_LDS16(A + (size_t)(row0 + m0) * K + k0 + g0 * 8, lA + c0 * 8);
        GLD_LDS16(A + (size_t)(row0 + m1) * K + k0 + g1 * 8, lA + c1 * 8);
        GLD_LDS16(Bp + ((size_t)(k0 / 8 + g0) * N + col0 + m0) * 8, lB + c0 * 8);
        GLD_LDS16(Bp + ((size_t)(k0 / 8 + g1) * N + col0 + m1) * 8, lB + c1 * 8);
        __syncthreads();
        bf16x8 af[4], bfr[4];
#pragma unroll
        for (int i = 0; i < 4; ++i) {
            af[i]  = *(const bf16x8*)&lA[(ko * 128 + wm + i * 16 + rl) * 8];
            bfr[i] = *(const bf16x8*)&lB[(ko * 128 + wn + i * 16 + rl) * 8];
        }
#pragma unroll
        for (int i = 0; i < 4; ++i)
#pragma unroll
            for (int j = 0; j < 4; ++j)
                acc[i][j] = __builtin_amdgcn_mfma_f32_16x16x32_bf16(af[i], bfr[j], acc[i][j], 0, 0, 0);
    }
    const int cr = (lane >> 4) * 4;
    const int cc = lane & 15;
#pragma unroll
    for (int i = 0; i < 4; ++i)
#pragma unroll
        for (int j = 0; j < 4; ++j) {
            const int col = col0 + wn + j * 16 + cc;
#pragma unroll
            for (int r = 0; r < 4; ++r) {
                const int row = row0 + wm + i * 16 + cr + r;
                C[(size_t)row * N + col] = (bf16_t)acc[i][j][r];
            }
        }
}

// ============ ft GEMM: hb @ Wfc_p -> ft8 (fp8) + fused el/er head-dots ============
__global__ __launch_bounds__(256) void gemm_ft(const bf16_t* __restrict__ A,
                                               const bf16_t* __restrict__ Bp,
                                               const float* __restrict__ attn_l,
                                               const float* __restrict__ attn_r,
                                               unsigned char* __restrict__ ft8,
                                               float* __restrict__ el,
                                               float* __restrict__ er) {
    __shared__ __align__(16) bf16_t lA[4096];
    __shared__ __align__(16) bf16_t lB[4096];
    __shared__ float s_el[2][128], s_er[2][128];
    const int tid = threadIdx.x, lane = tid & 63, wave = tid >> 6;
    const int wm = (wave >> 1) * 64, wn = (wave & 1) * 64;
    const int row0 = blockIdx.y * 128;
    const int head = blockIdx.x, col0 = head * 128;
    const int ko = lane >> 4, rl = lane & 15;
    f32x4 acc[4][4] = {};
    const int c0 = tid, c1 = tid + 256;
    const int g0 = c0 >> 7, m0 = c0 & 127;
    const int g1 = c1 >> 7, m1 = c1 & 127;
    for (int k0 = 0; k0 < 128; k0 += 32) {
        __syncthreads();
        GLD_LDS16(A + (size_t)(row0 + m0) * 128 + k0 + g0 * 8, lA + c0 * 8);
        GLD_LDS16(A + (size_t)(row0 + m1) * 128 + k0 + g1 * 8, lA + c1 * 8);
        GLD_LDS16(Bp + ((size_t)(k0 / 8 + g0) * 512 + col0 + m0) * 8, lB + c0 * 8);
        GLD_LDS16(Bp + ((size_t)(k0 / 8 + g1) * 512 + col0 + m1) * 8, lB + c1 * 8);
        __syncthreads();
        bf16x8 af[4], bfr[4];
#pragma unroll
        for (int i = 0; i < 4; ++i) {
            af[i]  = *(const bf16x8*)&lA[(ko * 128 + wm + i * 16 + rl) * 8];
            bfr[i] = *(const bf16x8*)&lB[(ko * 128 + wn + i * 16 + rl) * 8];
        }
#pragma unroll
        for (int i = 0; i < 4; ++i)
#pragma unroll
            for (int j = 0; j < 4; ++j)
                acc[i][j] = __builtin_amdgcn_mfma_f32_16x16x32_bf16(af[i], bfr[j], acc[i][j], 0, 0, 0);
    }
    const int cr = (lane >> 4) * 4, cc = lane & 15;
    float al[4], ar[4];
#pragma unroll
    for (int j = 0; j < 4; ++j) {
        al[j] = attn_l[col0 + wn + j * 16 + cc];
        ar[j] = attn_r[col0 + wn + j * 16 + cc];
    }
#pragma unroll
    for (int i = 0; i < 4; ++i)
#pragma unroll
        for (int r = 0; r < 4; ++r) {
            const int row = row0 + wm + i * 16 + cr + r;
            float pel = 0.f, per = 0.f;
#pragma unroll
            for (int j = 0; j < 4; ++j) {
                const float v = acc[i][j][r];
                ft8[(size_t)row * 512 + col0 + wn + j * 16 + cc] = f32_to_e4m3(v);
                pel += v * al[j];
                per += v * ar[j];
            }
#pragma unroll
            for (int m = 1; m < 16; m <<= 1) {
                pel += __shfl_xor(pel, m);
                per += __shfl_xor(per, m);
            }
            if (cc == 0) {
                s_el[wn >> 6][wm + i * 16 + cr + r] = pel;
                s_er[wn >> 6][wm + i * 16 + cr + r] = per;
            }
        }
    __syncthreads();
    if (tid < 128) {
        el[(size_t)(row0 + tid) * 4 + head] = s_el[0][tid] + s_el[1][tid];
        er[(size_t)(row0 + tid) * 4 + head] = s_er[0][tid] + s_er[1][tid];
    }
}

// ============ mha GEMM + LN1 fused: x3b = LN(h + relu(x1 @ Wmha + b_mha)) ============
__global__ __launch_bounds__(256) void gemm_mha_ln(const bf16_t* __restrict__ A,
                                                   const bf16_t* __restrict__ Bp,
                                                   const float* __restrict__ bias,
                                                   const float* __restrict__ h0,
                                                   const float* __restrict__ gamma,
                                                   const float* __restrict__ beta,
                                                   bf16_t* __restrict__ out) {
    __shared__ __align__(16) bf16_t lA[4096];
    __shared__ __align__(16) bf16_t lB[4096];
    __shared__ float s_s1[2][128], s_s2[2][128], s_mu[128], s_rs[128];
    const int tid = threadIdx.x, lane = tid & 63, wave = tid >> 6;
    const int wm = (wave >> 1) * 64, wn = (wave & 1) * 64;
    const int row0 = blockIdx.x * 128;
    const int ko = lane >> 4, rl = lane & 15;
    f32x4 acc[4][4] = {};
    const int c0 = tid, c1 = tid + 256;
    const int g0 = c0 >> 7, m0 = c0 & 127;
    const int g1 = c1 >> 7, m1 = c1 & 127;
    for (int k0 = 0; k0 < 512; k0 += 32) {
        __syncthreads();
        GLD_LDS16(A + (size_t)(row0 + m0) * 512 + k0 + g0 * 8, lA + c0 * 8);
        GLD_LDS16(A + (size_t)(row0 + m1) * 512 + k0 + g1 * 8, lA + c1 * 8);
        GLD_LDS16(Bp + ((size_t)(k0 / 8 + g0) * 128 + m0) * 8, lB + c0 * 8);
        GLD_LDS16(Bp + ((size_t)(k0 / 8 + g1) * 128 + m1) * 8, lB + c1 * 8);
        __syncthreads();
        bf16x8 af[4], bfr[4];
#pragma unroll
        for (int i = 0; i < 4; ++i) {
            af[i]  = *(const bf16x8*)&lA[(ko * 128 + wm + i * 16 + rl) * 8];
            bfr[i] = *(const bf16x8*)&lB[(ko * 128 + wn + i * 16 + rl) * 8];
        }
#pragma unroll
        for (int i = 0; i < 4; ++i)
#pragma unroll
            for (int j = 0; j < 4; ++j)
                acc[i][j] = __builtin_amdgcn_mfma_f32_16x16x32_bf16(af[i], bfr[j], acc[i][j], 0, 0, 0);
    }
    const int cr = (lane >> 4) * 4, cc = lane & 15;
#pragma unroll
    for (int j = 0; j < 4; ++j) {
        const int col = wn + j * 16 + cc;
        const float bb = bias[col];
#pragma unroll
        for (int i = 0; i < 4; ++i)
#pragma unroll
            for (int r = 0; r < 4; ++r) {
                const int row = row0 + wm + i * 16 + cr + r;
                acc[i][j][r] = fmaxf(acc[i][j][r] + bb, 0.f) + h0[(size_t)row * 128 + col];
            }
    }
#pragma unroll
    for (int i = 0; i < 4; ++i)
#pragma unroll
        for (int r = 0; r < 4; ++r) {
            float s1 = 0.f, s2 = 0.f;
#pragma unroll
            for (int j = 0; j < 4; ++j) { const float v = acc[i][j][r]; s1 += v; s2 += v * v; }
#pragma unroll
            for (int m = 1; m < 16; m <<= 1) {
                s1 += __shfl_xor(s1, m);
                s2 += __shfl_xor(s2, m);
            }
            if (cc == 0) {
                s_s1[wn >> 6][wm + i * 16 + cr + r] = s1;
                s_s2[wn >> 6][wm + i * 16 + cr + r] = s2;
            }
        }
    __syncthreads();
    if (tid < 128) {
        const float a = s_s1[0][tid] + s_s1[1][tid];
        const float q = s_s2[0][tid] + s_s2[1][tid];
        const float mu = a * (1.f / 128.f);
        s_mu[tid] = mu;
        s_rs[tid] = rsqrtf(q * (1.f / 128.f) - mu * mu + LN_EPS);
    }
    __syncthreads();
#pragma unroll
    for (int j = 0; j < 4; ++j) {
        const int col = wn + j * 16 + cc;
        const float gg = gamma[col], bb = beta[col];
#pragma unroll
        for (int i = 0; i < 4; ++i)
#pragma unroll
            for (int r = 0; r < 4; ++r) {
                const int rloc = wm + i * 16 + cr + r;
                out[(size_t)(row0 + rloc) * 128 + col] =
                    (bf16_t)((acc[i][j][r] - s_mu[rloc]) * s_rs[rloc] * gg + bb);
            }
    }
}

// ============ fused FFN + LN2 (v2): pipelined, A-frags in VGPR, dbuf weights ============
// grid 256, 128 rows/block, 4 waves, 32 chunks of 64 dff. y never hits HBM.
__global__ __launch_bounds__(256, 1) void ffn_fused(const bf16_t* __restrict__ x3,
                                                    const bf16_t* __restrict__ W1p,
                                                    const float* __restrict__ b1,
                                                    const bf16_t* __restrict__ W2p,
                                                    const float* __restrict__ b2,
                                                    const float* __restrict__ gamma,
                                                    const float* __restrict__ beta,
                                                    float* __restrict__ out) {
    __shared__ __align__(16) bf16_t lX[16384];      // [g16][128][8]   32KB (epilogue residual + afx source)
    __shared__ __align__(16) bf16_t lW1[2][8192];   // [g16][64][8]    16KB x2
    __shared__ __align__(16) bf16_t lW2[2][8192];   // [g8][128][8]    16KB x2
    __shared__ __align__(16) bf16_t lY[8192];       // [g8][128][8]    16KB
    __shared__ float s_s1[2][128], s_s2[2][128], s_mu[128], s_rs[128];
    const int tid = threadIdx.x, lane = tid & 63, wave = tid >> 6;
    const int wm = (wave >> 1) * 64;          // row half
    const int wn1 = (wave & 1) * 32;          // G1 dff half (32 cols)
    const int wn2 = (wave & 1) * 64;          // G2 hid half (64 cols)
    const int row0 = blockIdx.x * 128;
    const int ko = lane >> 4, rl = lane & 15;
    const int cr = ko * 4, cc = rl;

    // prologue: stage x3 tile + chunk-0 weights
#pragma unroll
    for (int it = 0; it < 8; ++it) {
        const int c = it * 256 + tid, g = c >> 7, m = c & 127;
        GLD_LDS16(x3 + (size_t)(row0 + m) * 128 + g * 8, lX + c * 8);
    }
#pragma unroll
    for (int it = 0; it < 4; ++it) {
        const int c = it * 256 + tid;
        { const int g = c >> 6, n = c & 63;  GLD_LDS16(W1p + ((size_t)g * 2048 + n) * 8, lW1[0] + c * 8); }
        { const int g = c >> 7, n = c & 127; GLD_LDS16(W2p + ((size_t)g * 128 + n) * 8, lW2[0] + c * 8); }
    }
    __syncthreads();
    // x3 A-fragments -> VGPRs, persistent
    bf16x8 afx[4][4];
#pragma unroll
    for (int i = 0; i < 4; ++i)
#pragma unroll
        for (int kk = 0; kk < 4; ++kk)
            afx[i][kk] = *(const bf16x8*)&lX[((kk * 4 + ko) * 128 + wm + i * 16 + rl) * 8];

    f32x4 xacc[4][4] = {};
    for (int ch = 0; ch < 32; ++ch) {
        const int b = ch & 1;
        // GEMM1: y[128 x 64dff] tile = x3 @ W1chunk (A from VGPR)
        f32x4 yacc[4][2] = {};
#pragma unroll
        for (int kk = 0; kk < 4; ++kk) {
            bf16x8 bfr[2];
#pragma unroll
            for (int j = 0; j < 2; ++j)
                bfr[j] = *(const bf16x8*)&lW1[b][((kk * 4 + ko) * 64 + wn1 + j * 16 + rl) * 8];
#pragma unroll
            for (int i = 0; i < 4; ++i)
#pragma unroll
                for (int j = 0; j < 2; ++j)
                    yacc[i][j] = __builtin_amdgcn_mfma_f32_16x16x32_bf16(afx[i][kk], bfr[j], yacc[i][j], 0, 0, 0);
        }
        // relu+bias -> lY (A-frag layout [dff/8][row][8])
#pragma unroll
        for (int j = 0; j < 2; ++j) {
            const int dff = wn1 + j * 16 + cc;
            const float bb = b1[ch * 64 + dff];
#pragma unroll
            for (int i = 0; i < 4; ++i)
#pragma unroll
                for (int r = 0; r < 4; ++r)
                    lY[((dff >> 3) * 128 + wm + i * 16 + cr + r) * 8 + (dff & 7)] =
                        (bf16_t)fmaxf(yacc[i][j][r] + bb, 0.f);
        }
        __syncthreads();                     // lY visible; chunk-ch weights already drained earlier
        // prefetch next chunk's weights into other buffer (streams during GEMM2)
        if (ch + 1 < 32) {
            const int nb = b ^ 1, nch = ch + 1;
#pragma unroll
            for (int it = 0; it < 4; ++it) {
                const int c = it * 256 + tid;
                { const int g = c >> 6, n = c & 63;  GLD_LDS16(W1p + ((size_t)g * 2048 + nch * 64 + n) * 8, lW1[nb] + c * 8); }
                { const int g = c >> 7, n = c & 127; GLD_LDS16(W2p + ((size_t)(nch * 8 + g) * 128 + n) * 8, lW2[nb] + c * 8); }
            }
        }
        // GEMM2: xacc += y @ W2chunk
#pragma unroll
        for (int kk = 0; kk < 2; ++kk) {
            bf16x8 afY[4], bfr2[4];
#pragma unroll
            for (int i = 0; i < 4; ++i)
                afY[i] = *(const bf16x8*)&lY[((kk * 4 + ko) * 128 + wm + i * 16 + rl) * 8];
#pragma unroll
            for (int j = 0; j < 4; ++j)
                bfr2[j] = *(const bf16x8*)&lW2[b][((kk * 4 + ko) * 128 + wn2 + j * 16 + rl) * 8];
#pragma unroll
            for (int i = 0; i < 4; ++i)
#pragma unroll
                for (int j = 0; j < 4; ++j)
                    xacc[i][j] = __builtin_amdgcn_mfma_f32_16x16x32_bf16(afY[i], bfr2[j], xacc[i][j], 0, 0, 0);
        }
        __syncthreads();                     // drains prefetch; frees lY & lW[b]
    }
    // epilogue: + b2 + x3 residual, LN2, store fp32
#pragma unroll
    for (int j = 0; j < 4; ++j) {
        const int col = wn2 + j * 16 + cc;
        const float bb = b2[col];
#pragma unroll
        for (int i = 0; i < 4; ++i)
#pragma unroll
            for (int r = 0; r < 4; ++r) {
                const int rloc = wm + i * 16 + cr + r;
                const float x3v = (float)lX[((col >> 3) * 128 + rloc) * 8 + (col & 7)];
                xacc[i][j][r] += bb + x3v;
            }
    }
#pragma unroll
    for (int i = 0; i < 4; ++i)
#pragma unroll
        for (int r = 0; r < 4; ++r) {
            float s1 = 0.f, s2 = 0.f;
#pragma unroll
            for (int j = 0; j < 4; ++j) { const float v = xacc[i][j][r]; s1 += v; s2 += v * v; }
#pragma unroll
            for (int m = 1; m < 16; m <<= 1) {
                s1 += __shfl_xor(s1, m);
                s2 += __shfl_xor(s2, m);
            }
            if (cc == 0) {
                s_s1[wn2 >> 6][wm + i * 16 + cr + r] = s1;
                s_s2[wn2 >> 6][wm + i * 16 + cr + r] = s2;
            }
        }
    __syncthreads();
    if (tid < 128) {
        const float a = s_s1[0][tid] + s_s1[1][tid];
        const float q = s_s2[0][tid] + s_s2[1][tid];
        const float mu = a * (1.f / 128.f);
        s_mu[tid] = mu;
        s_rs[tid] = rsqrtf(q * (1.f / 128.f) - mu * mu + LN_EPS);
    }
    __syncthreads();
#pragma unroll
    for (int j = 0; j < 4; ++j) {
        const int col = wn2 + j * 16 + cc;
        const float gg = gamma[col], bb = beta[col];
#pragma unroll
        for (int i = 0; i < 4; ++i)
#pragma unroll
            for (int r = 0; r < 4; ++r) {
                const int rloc = wm + i * 16 + cr + r;
                out[(size_t)(row0 + rloc) * 128 + col] =
                    (xacc[i][j][r] - s_mu[rloc]) * s_rs[rloc] * gg + bb;
            }
    }
}

// ============ edge build: w = exp(leaky(score)); scatter into CSR slots ============
__global__ __launch_bounds__(256) void edge_build(const float* __restrict__ evals,
                                                  const int* __restrict__ src,
                                                  const int* __restrict__ dst,
                                                  const float* __restrict__ el,
                                                  const float* __restrict__ er,
                                                  const float* __restrict__ ce,
                                                  int* __restrict__ cursor,
                                                  int* __restrict__ csr_src,
                                                  float4* __restrict__ csr_w) {
    const int e = blockIdx.x * 256 + threadIdx.x;
    const int s = src[e], d = dst[e];
    const float ev = evals[e];
    const float4 l = *(const float4*)(el + (size_t)s * 4);
    const float4 r = *(const float4*)(er + (size_t)d * 4);
    const float4 c = *(const float4*)ce;
    float4 w;
    {
        float v;
        v = l.x + r.x + ev * c.x; v = v >= 0.f ? v : SLOPE * v; w.x = __expf(v);
        v = l.y + r.y + ev * c.y; v = v >= 0.f ? v : SLOPE * v; w.y = __expf(v);
        v = l.z + r.z + ev * c.z; v = v >= 0.f ? v : SLOPE * v; w.z = __expf(v);
        v = l.w + r.w + ev * c.w; v = v >= 0.f ? v : SLOPE * v; w.w = __expf(v);
    }
    const int pos = atomicAdd(&cursor[d], 1);
    if (pos < CAP) {
        csr_src[(size_t)d * CAP + pos] = s;
        csr_w[(size_t)d * CAP + pos] = w;
    }
}

// ============ aggregate (fp8 gather): x1 = relu((Σ w*ft[src])/Σw + res + bias) ============
__global__ __launch_bounds__(128) void aggregate_kernel(const unsigned char* __restrict__ ft8,
                                                        const bf16_t* __restrict__ res,
                                                        const int* __restrict__ cursor,
                                                        const int* __restrict__ csr_src,
                                                        const float4* __restrict__ csr_w,
                                                        const float* __restrict__ gat_bias,
                                                        bf16_t* __restrict__ x1) {
    const int n = blockIdx.x, t = threadIdx.x;
    __shared__ int s_src[CAP];
    __shared__ float s_w[CAP][4];
    const int deg = min(cursor[n], CAP);
    const int ht = t >> 5;
    if (t < deg) {
        s_src[t] = csr_src[(size_t)n * CAP + t];
        *(float4*)s_w[t] = csr_w[(size_t)n * CAP + t];
    }
    __syncthreads();
    float4 acc = {0.f, 0.f, 0.f, 0.f};
    float z = 0.f;
    for (int j = 0; j < deg; ++j) {
        const float w = s_w[j][ht];
        z += w;
        const unsigned u = *(const unsigned*)(ft8 + (size_t)s_src[j] * 512 + t * 4);
        const f32x2 lo = e4m3x2_to_f32<false>(u);
        const f32x2 hi = e4m3x2_to_f32<true>(u);
        acc.x += w * lo[0]; acc.y += w * lo[1];
        acc.z += w * hi[0]; acc.w += w * hi[1];
    }
    const float rz = deg > 0 ? 1.f / z : 0.f;
    const uint2 ur = *(const uint2*)(res + (size_t)n * FDIM + t * 4);
    const float4 gb = ((const float4*)gat_bias)[t];
    union { bf16_t b[4]; uint2 u; } pk;
    pk.b[0] = (bf16_t)fmaxf(acc.x * rz + __uint_as_float(ur.x << 16) + gb.x, 0.f);
    pk.b[1] = (bf16_t)fmaxf(acc.y * rz + __uint_as_float(ur.x & 0xFFFF0000u) + gb.y, 0.f);
    pk.b[2] = (bf16_t)fmaxf(acc.z * rz + __uint_as_float(ur.y << 16) + gb.z, 0.f);
    pk.b[3] = (bf16_t)fmaxf(acc.w * rz + __uint_as_float(ur.y & 0xFFFF0000u) + gb.w, 0.f);
    *(uint2*)(x1 + (size_t)n * FDIM + t * 4) = pk.u;
}

extern "C" void kernel_launch(void* const* d_in, const int* in_sizes, int n_in,
                              void* d_out, int out_size, void* d_ws, size_t ws_size,
                              hipStream_t stream) {
    const float* h        = (const float*)d_in[0];
    const float* evals    = (const float*)d_in[1];
    const int*   src      = (const int*)d_in[2];
    const int*   dst      = (const int*)d_in[3];
    const float* W_fc     = (const float*)d_in[5];
    const float* attn_l   = (const float*)d_in[6];
    const float* attn_r   = (const float*)d_in[7];
    const float* W_fe     = (const float*)d_in[8];
    const float* attn_e   = (const float*)d_in[9];
    const float* W_res    = (const float*)d_in[10];
    const float* gat_bias = (const float*)d_in[11];
    const float* W_mha    = (const float*)d_in[12];
    const float* b_mha    = (const float*)d_in[13];
    const float* n1_g     = (const float*)d_in[14];
    const float* n1_b     = (const float*)d_in[15];
    const float* n2_g     = (const float*)d_in[16];
    const float* n2_b     = (const float*)d_in[17];
    const float* W1       = (const float*)d_in[18];
    const float* b1       = (const float*)d_in[19];
    const float* W2       = (const float*)d_in[20];
    const float* b2       = (const float*)d_in[21];

    char* ws = (char*)d_ws;
    unsigned char* ft8 = (unsigned char*)(ws + 0);   // 16MB  N x 512 fp8
    bf16_t* res     = (bf16_t*)(ws + 16777216ull);   // 32MB  N x 512
    bf16_t* x1      = (bf16_t*)(ws + 50331648ull);   // 32MB  N x 512
    float4* csr_w   = (float4*)(ws + 83886080ull);   // 32MB  N x CAP x 16B
    int*    csr_src = (int*)   (ws + 117440512ull);  // 8MB   N x CAP
    bf16_t* x3b     = (bf16_t*)(ws + 125829120ull);  // 8MB   N x 128
    bf16_t* hb      = (bf16_t*)(ws + 134217728ull);  // 8MB   N x 128
    bf16_t* Wfc_p   = (bf16_t*)(ws + 142606336ull);  // 128KB
    bf16_t* Wres_p  = (bf16_t*)(ws + 142737408ull);  // 128KB
    bf16_t* Wmha_p  = (bf16_t*)(ws + 142868480ull);  // 128KB
    bf16_t* W1_p    = (bf16_t*)(ws + 142999552ull);  // 512KB
    bf16_t* W2_p    = (bf16_t*)(ws + 143523840ull);  // 512KB
    float*  el      = (float*) (ws + 144048128ull);  // 512KB
    float*  er      = (float*) (ws + 144572416ull);  // 512KB
    float*  ce      = (float*) (ws + 145096704ull);  // 16B
    int*    cursor  = (int*)   (ws + 145096768ull);  // 128KB

    if (ws_size < 146000000ull) return;

    (void)hipMemsetAsync(cursor, 0, 131072, stream);

    prep_kernel<<<4449, 256, 0, stream>>>(h, hb, W_fc, Wfc_p, W_res, Wres_p,
                                          W_mha, Wmha_p, W1, W1_p, W2, W2_p,
                                          W_fe, attn_e, ce);
    gemm_ft<<<dim3(4, 256), 256, 0, stream>>>(hb, Wfc_p, attn_l, attn_r, ft8, el, er);
    gemm_mfma<<<dim3(4, 256), 256, 0, stream>>>(hb, Wres_p, res, N_NODES, FDIM, 128);
    edge_build<<<E_EDGES / 256, 256, 0, stream>>>(evals, src, dst, el, er, ce, cursor, csr_src, csr_w);
    aggregate_kernel<<<N_NODES, 128, 0, stream>>>(ft8, res, cursor, csr_src, csr_w, gat_bias, x1);
    gemm_mha_ln<<<256, 256, 0, stream>>>(x1, Wmha_p, b_mha, h, n1_g, n1_b, x3b);
    ffn_fused<<<256, 256, 0, stream>>>(x3b, W1_p, b1, W2_p, b2, n2_g, n2_b, (float*)d_out);
}

// Round 7
// 297.701 us; speedup vs baseline: 1.1040x; 1.1040x over previous
//
#include <hip/hip_runtime.h>
#include <hip/hip_bf16.h>

#define N_NODES 32768
#define E_EDGES 524288
#define HIDDIM 128
#define FDIM 512
#define DFF 2048
#define LN_EPS 1e-5f
#define SLOPE 0.2f
#define CAP 64          // CSR slot capacity per dst (Poisson(16): P(>64) ~ 1e-19)

typedef __bf16 bf16_t;
typedef __bf16 bf16x8 __attribute__((ext_vector_type(8)));
typedef float f32x4 __attribute__((ext_vector_type(4)));
typedef float f32x2 __attribute__((ext_vector_type(2)));

#define GLD_LDS16(gp, lp) __builtin_amdgcn_global_load_lds( \
    (const __attribute__((address_space(1))) unsigned int*)(gp), \
    (__attribute__((address_space(3))) unsigned int*)(lp), 16, 0, 0)

// ---------- fp8 e4m3 codec (HW cvt when available) ----------
__device__ inline unsigned char f32_to_e4m3(float v) {
#if __has_builtin(__builtin_amdgcn_cvt_pk_fp8_f32)
    return (unsigned char)(__builtin_amdgcn_cvt_pk_fp8_f32(v, v, 0, false) & 0xff);
#else
    unsigned bits = __float_as_uint(v);
    unsigned sign = (bits >> 24) & 0x80;
    float av = fabsf(v);
    if (av >= 448.f) return (unsigned char)(sign | 0x7E);
    int e = (int)((bits >> 23) & 0xFF) - 127;
    if (e < -6) { int n = (int)rintf(av * 512.f); return (unsigned char)(sign | n); }
    float ulp = exp2f((float)(e - 3));
    int n = (int)rintf(av / ulp);
    if (n == 16) { e += 1; n = 8; }
    return (unsigned char)(sign | ((e + 7) << 3) | (n - 8));
#endif
}
template<bool HI>
__device__ inline f32x2 e4m3x2_to_f32(unsigned u) {
#if __has_builtin(__builtin_amdgcn_cvt_pk_f32_fp8)
    return __builtin_amdgcn_cvt_pk_f32_fp8(u, HI);
#else
    f32x2 r;
    unsigned b0 = HI ? ((u >> 16) & 0xff) : (u & 0xff);
    unsigned b1 = HI ? ((u >> 24) & 0xff) : ((u >> 8) & 0xff);
    unsigned bs[2] = {b0, b1};
    for (int i = 0; i < 2; ++i) {
        unsigned b = bs[i];
        float s = (b & 0x80) ? -1.f : 1.f;
        int e = (b >> 3) & 15, m = b & 7;
        float v = e ? (8 + m) * exp2f((float)(e - 10)) : m * exp2f(-9.f);
        r[i] = s * v;
    }
    return r;
#endif
}

// ============ prep: h->bf16, all weight k8-packs, ce — one dispatch ============
__device__ inline void pack_range(const float* __restrict__ B, bf16_t* __restrict__ out,
                                  int id, int N) {
    const int g = id / N, n = id % N;
    union { bf16_t b[8]; uint4 u; } pk;
#pragma unroll
    for (int j = 0; j < 8; ++j) pk.b[j] = (bf16_t)B[(size_t)(g * 8 + j) * N + n];
    *(uint4*)(out + (size_t)id * 8) = pk.u;
}

__global__ __launch_bounds__(256) void prep_kernel(const float* __restrict__ h, bf16_t* __restrict__ hb,
                                                   const float* __restrict__ W_fc, bf16_t* __restrict__ Wfc_p,
                                                   const float* __restrict__ W_res, bf16_t* __restrict__ Wres_p,
                                                   const float* __restrict__ W_mha, bf16_t* __restrict__ Wmha_p,
                                                   const float* __restrict__ W1, bf16_t* __restrict__ W1_p,
                                                   const float* __restrict__ W2, bf16_t* __restrict__ W2_p,
                                                   const float* __restrict__ W_fe, const float* __restrict__ attn_e,
                                                   float* __restrict__ ce) {
    int bid = blockIdx.x;
    const int tid = threadIdx.x;
    if (bid < 4096) {                       // h fp32 -> bf16 (4 elems/thread)
        const int id = bid * 256 + tid;
        const float4 v = ((const float4*)h)[id];
        union { bf16_t b[4]; uint2 u; } pk;
        pk.b[0] = (bf16_t)v.x; pk.b[1] = (bf16_t)v.y; pk.b[2] = (bf16_t)v.z; pk.b[3] = (bf16_t)v.w;
        *(uint2*)(hb + (size_t)id * 4) = pk.u;
        return;
    }
    bid -= 4096;
    if (bid < 32)  { pack_range(W_fc,  Wfc_p,  bid * 256 + tid, 512);  return; }
    bid -= 32;
    if (bid < 32)  { pack_range(W_res, Wres_p, bid * 256 + tid, 512);  return; }
    bid -= 32;
    if (bid < 32)  { pack_range(W_mha, Wmha_p, bid * 256 + tid, 128);  return; }
    bid -= 32;
    if (bid < 128) { pack_range(W1,    W1_p,   bid * 256 + tid, 2048); return; }
    bid -= 128;
    if (bid < 128) { pack_range(W2,    W2_p,   bid * 256 + tid, 128);  return; }
    // ce
    if (tid < 128) {
        const float4 w = ((const float4*)W_fe)[tid];
        const float4 a = ((const float4*)attn_e)[tid];
        float p = w.x * a.x + w.y * a.y + w.z * a.z + w.w * a.w;
        for (int off = 16; off; off >>= 1) p += __shfl_down(p, off, 32);
        if ((tid & 31) == 0) ce[tid >> 5] = p;
    }
}

// ============ generic bf16 MFMA GEMM (used for res): C bf16 = A @ Bp ============
__global__ __launch_bounds__(256) void gemm_mfma(const bf16_t* __restrict__ A,
                                                 const bf16_t* __restrict__ Bp,
                                                 bf16_t* __restrict__ C,
                                                 int M, int N, int K) {
    __shared__ __align__(16) bf16_t lA[4096];
    __shared__ __align__(16) bf16_t lB[4096];
    const int tid = threadIdx.x;
    const int lane = tid & 63;
    const int wave = tid >> 6;
    const int wm = (wave >> 1) * 64, wn = (wave & 1) * 64;
    const int row0 = blockIdx.y * 128, col0 = blockIdx.x * 128;
    const int ko = lane >> 4;
    const int rl = lane & 15;
    f32x4 acc[4][4] = {};
    const int c0 = tid, c1 = tid + 256;
    const int g0 = c0 >> 7, m0 = c0 & 127;
    const int g1 = c1 >> 7, m1 = c1 & 127;
    for (int k0 = 0; k0 < K; k0 += 32) {
        __syncthreads();
        GLD_LDS16(A + (size_t)(row0 + m0) * K + k0 + g0 * 8, lA + c0 * 8);
        GLD_LDS16(A + (size_t)(row0 + m1) * K + k0 + g1 * 8, lA + c1 * 8);
        GLD_LDS16(Bp + ((size_t)(k0 / 8 + g0) * N + col0 + m0) * 8, lB + c0 * 8);
        GLD_LDS16(Bp + ((size_t)(k0 / 8 + g1) * N + col0 + m1) * 8, lB + c1 * 8);
        __syncthreads();
        bf16x8 af[4], bfr[4];
#pragma unroll
        for (int i = 0; i < 4; ++i) {
            af[i]  = *(const bf16x8*)&lA[(ko * 128 + wm + i * 16 + rl) * 8];
            bfr[i] = *(const bf16x8*)&lB[(ko * 128 + wn + i * 16 + rl) * 8];
        }
#pragma unroll
        for (int i = 0; i < 4; ++i)
#pragma unroll
            for (int j = 0; j < 4; ++j)
                acc[i][j] = __builtin_amdgcn_mfma_f32_16x16x32_bf16(af[i], bfr[j], acc[i][j], 0, 0, 0);
    }
    const int cr = (lane >> 4) * 4;
    const int cc = lane & 15;
#pragma unroll
    for (int i = 0; i < 4; ++i)
#pragma unroll
        for (int j = 0; j < 4; ++j) {
            const int col = col0 + wn + j * 16 + cc;
#pragma unroll
            for (int r = 0; r < 4; ++r) {
                const int row = row0 + wm + i * 16 + cr + r;
                C[(size_t)row * N + col] = (bf16_t)acc[i][j][r];
            }
        }
}

// ============ ft GEMM: hb @ Wfc_p -> ft8 (fp8) + fused el/er head-dots ============
__global__ __launch_bounds__(256) void gemm_ft(const bf16_t* __restrict__ A,
                                               const bf16_t* __restrict__ Bp,
                                               const float* __restrict__ attn_l,
                                               const float* __restrict__ attn_r,
                                               unsigned char* __restrict__ ft8,
                                               float* __restrict__ el,
                                               float* __restrict__ er) {
    __shared__ __align__(16) bf16_t lA[4096];
    __shared__ __align__(16) bf16_t lB[4096];
    __shared__ float s_el[2][128], s_er[2][128];
    const int tid = threadIdx.x, lane = tid & 63, wave = tid >> 6;
    const int wm = (wave >> 1) * 64, wn = (wave & 1) * 64;
    const int row0 = blockIdx.y * 128;
    const int head = blockIdx.x, col0 = head * 128;
    const int ko = lane >> 4, rl = lane & 15;
    f32x4 acc[4][4] = {};
    const int c0 = tid, c1 = tid + 256;
    const int g0 = c0 >> 7, m0 = c0 & 127;
    const int g1 = c1 >> 7, m1 = c1 & 127;
    for (int k0 = 0; k0 < 128; k0 += 32) {
        __syncthreads();
        GLD_LDS16(A + (size_t)(row0 + m0) * 128 + k0 + g0 * 8, lA + c0 * 8);
        GLD_LDS16(A + (size_t)(row0 + m1) * 128 + k0 + g1 * 8, lA + c1 * 8);
        GLD_LDS16(Bp + ((size_t)(k0 / 8 + g0) * 512 + col0 + m0) * 8, lB + c0 * 8);
        GLD_LDS16(Bp + ((size_t)(k0 / 8 + g1) * 512 + col0 + m1) * 8, lB + c1 * 8);
        __syncthreads();
        bf16x8 af[4], bfr[4];
#pragma unroll
        for (int i = 0; i < 4; ++i) {
            af[i]  = *(const bf16x8*)&lA[(ko * 128 + wm + i * 16 + rl) * 8];
            bfr[i] = *(const bf16x8*)&lB[(ko * 128 + wn + i * 16 + rl) * 8];
        }
#pragma unroll
        for (int i = 0; i < 4; ++i)
#pragma unroll
            for (int j = 0; j < 4; ++j)
                acc[i][j] = __builtin_amdgcn_mfma_f32_16x16x32_bf16(af[i], bfr[j], acc[i][j], 0, 0, 0);
    }
    const int cr = (lane >> 4) * 4, cc = lane & 15;
    float al[4], ar[4];
#pragma unroll
    for (int j = 0; j < 4; ++j) {
        al[j] = attn_l[col0 + wn + j * 16 + cc];
        ar[j] = attn_r[col0 + wn + j * 16 + cc];
    }
#pragma unroll
    for (int i = 0; i < 4; ++i)
#pragma unroll
        for (int r = 0; r < 4; ++r) {
            const int row = row0 + wm + i * 16 + cr + r;
            float pel = 0.f, per = 0.f;
#pragma unroll
            for (int j = 0; j < 4; ++j) {
                const float v = acc[i][j][r];
                ft8[(size_t)row * 512 + col0 + wn + j * 16 + cc] = f32_to_e4m3(v);
                pel += v * al[j];
                per += v * ar[j];
            }
#pragma unroll
            for (int m = 1; m < 16; m <<= 1) {
                pel += __shfl_xor(pel, m);
                per += __shfl_xor(per, m);
            }
            if (cc == 0) {
                s_el[wn >> 6][wm + i * 16 + cr + r] = pel;
                s_er[wn >> 6][wm + i * 16 + cr + r] = per;
            }
        }
    __syncthreads();
    if (tid < 128) {
        el[(size_t)(row0 + tid) * 4 + head] = s_el[0][tid] + s_el[1][tid];
        er[(size_t)(row0 + tid) * 4 + head] = s_er[0][tid] + s_er[1][tid];
    }
}

// ============ mha GEMM + LN1 fused: x3b = LN(h + relu(x1 @ Wmha + b_mha)) ============
__global__ __launch_bounds__(256) void gemm_mha_ln(const bf16_t* __restrict__ A,
                                                   const bf16_t* __restrict__ Bp,
                                                   const float* __restrict__ bias,
                                                   const float* __restrict__ h0,
                                                   const float* __restrict__ gamma,
                                                   const float* __restrict__ beta,
                                                   bf16_t* __restrict__ out) {
    __shared__ __align__(16) bf16_t lA[4096];
    __shared__ __align__(16) bf16_t lB[4096];
    __shared__ float s_s1[2][128], s_s2[2][128], s_mu[128], s_rs[128];
    const int tid = threadIdx.x, lane = tid & 63, wave = tid >> 6;
    const int wm = (wave >> 1) * 64, wn = (wave & 1) * 64;
    const int row0 = blockIdx.x * 128;
    const int ko = lane >> 4, rl = lane & 15;
    f32x4 acc[4][4] = {};
    const int c0 = tid, c1 = tid + 256;
    const int g0 = c0 >> 7, m0 = c0 & 127;
    const int g1 = c1 >> 7, m1 = c1 & 127;
    for (int k0 = 0; k0 < 512; k0 += 32) {
        __syncthreads();
        GLD_LDS16(A + (size_t)(row0 + m0) * 512 + k0 + g0 * 8, lA + c0 * 8);
        GLD_LDS16(A + (size_t)(row0 + m1) * 512 + k0 + g1 * 8, lA + c1 * 8);
        GLD_LDS16(Bp + ((size_t)(k0 / 8 + g0) * 128 + m0) * 8, lB + c0 * 8);
        GLD_LDS16(Bp + ((size_t)(k0 / 8 + g1) * 128 + m1) * 8, lB + c1 * 8);
        __syncthreads();
        bf16x8 af[4], bfr[4];
#pragma unroll
        for (int i = 0; i < 4; ++i) {
            af[i]  = *(const bf16x8*)&lA[(ko * 128 + wm + i * 16 + rl) * 8];
            bfr[i] = *(const bf16x8*)&lB[(ko * 128 + wn + i * 16 + rl) * 8];
        }
#pragma unroll
        for (int i = 0; i < 4; ++i)
#pragma unroll
            for (int j = 0; j < 4; ++j)
                acc[i][j] = __builtin_amdgcn_mfma_f32_16x16x32_bf16(af[i], bfr[j], acc[i][j], 0, 0, 0);
    }
    const int cr = (lane >> 4) * 4, cc = lane & 15;
#pragma unroll
    for (int j = 0; j < 4; ++j) {
        const int col = wn + j * 16 + cc;
        const float bb = bias[col];
#pragma unroll
        for (int i = 0; i < 4; ++i)
#pragma unroll
            for (int r = 0; r < 4; ++r) {
                const int row = row0 + wm + i * 16 + cr + r;
                acc[i][j][r] = fmaxf(acc[i][j][r] + bb, 0.f) + h0[(size_t)row * 128 + col];
            }
    }
#pragma unroll
    for (int i = 0; i < 4; ++i)
#pragma unroll
        for (int r = 0; r < 4; ++r) {
            float s1 = 0.f, s2 = 0.f;
#pragma unroll
            for (int j = 0; j < 4; ++j) { const float v = acc[i][j][r]; s1 += v; s2 += v * v; }
#pragma unroll
            for (int m = 1; m < 16; m <<= 1) {
                s1 += __shfl_xor(s1, m);
                s2 += __shfl_xor(s2, m);
            }
            if (cc == 0) {
                s_s1[wn >> 6][wm + i * 16 + cr + r] = s1;
                s_s2[wn >> 6][wm + i * 16 + cr + r] = s2;
            }
        }
    __syncthreads();
    if (tid < 128) {
        const float a = s_s1[0][tid] + s_s1[1][tid];
        const float q = s_s2[0][tid] + s_s2[1][tid];
        const float mu = a * (1.f / 128.f);
        s_mu[tid] = mu;
        s_rs[tid] = rsqrtf(q * (1.f / 128.f) - mu * mu + LN_EPS);
    }
    __syncthreads();
#pragma unroll
    for (int j = 0; j < 4; ++j) {
        const int col = wn + j * 16 + cc;
        const float gg = gamma[col], bb = beta[col];
#pragma unroll
        for (int i = 0; i < 4; ++i)
#pragma unroll
            for (int r = 0; r < 4; ++r) {
                const int rloc = wm + i * 16 + cr + r;
                out[(size_t)(row0 + rloc) * 128 + col] =
                    (bf16_t)((acc[i][j][r] - s_mu[rloc]) * s_rs[rloc] * gg + bb);
            }
    }
}

// ============ fused FFN + LN2 (v3): 64-row blocks, grid 512, ~42KB LDS, 2 blocks/CU ============
// Cross-block wave overlap hides barrier drains (m114). y never hits HBM.
__global__ __launch_bounds__(256, 2) void ffn_fused(const bf16_t* __restrict__ x3,
                                                    const bf16_t* __restrict__ W1p,
                                                    const float* __restrict__ b1,
                                                    const bf16_t* __restrict__ W2p,
                                                    const float* __restrict__ b2,
                                                    const float* __restrict__ gamma,
                                                    const float* __restrict__ beta,
                                                    float* __restrict__ out) {
    __shared__ __align__(16) bf16_t lW1[8192];   // [g16][64][8]  16KB (also x3 staging at start)
    __shared__ __align__(16) bf16_t lW2[8192];   // [g8][128][8]  16KB
    __shared__ __align__(16) bf16_t lY[4096];    // [g8][64][8]    8KB
    __shared__ float s_s1[2][64], s_s2[2][64], s_mu[64], s_rs[64];
    const int tid = threadIdx.x, lane = tid & 63, wave = tid >> 6;
    const int wr  = (wave >> 1) * 32;   // row offset within 64
    const int wc1 = (wave & 1) * 32;    // GEMM1 dff cols within chunk 64
    const int wc2 = (wave & 1) * 64;    // GEMM2 hid cols within 128
    const int row0 = blockIdx.x * 64;
    const int ko = lane >> 4, rl = lane & 15;
    const int cr = ko * 4, cc = rl;

    // stage x3 (64x128) into lW1 region, lift A-frags to VGPRs
#pragma unroll
    for (int it = 0; it < 4; ++it) {
        const int c = it * 256 + tid, g = c >> 6, m = c & 63;
        GLD_LDS16(x3 + (size_t)(row0 + m) * 128 + g * 8, lW1 + c * 8);
    }
    __syncthreads();
    bf16x8 afx[2][4];
#pragma unroll
    for (int i = 0; i < 2; ++i)
#pragma unroll
        for (int kk = 0; kk < 4; ++kk)
            afx[i][kk] = *(const bf16x8*)&lW1[((kk * 4 + ko) * 64 + wr + i * 16 + rl) * 8];

    f32x4 xacc[2][4] = {};
    for (int ch = 0; ch < 32; ++ch) {
        __syncthreads();   // prior chunk's lW/lY reads done (and afx reads at ch=0)
#pragma unroll
        for (int it = 0; it < 4; ++it) {
            const int c = it * 256 + tid;
            { const int g = c >> 6, n = c & 63;  GLD_LDS16(W1p + ((size_t)g * 2048 + ch * 64 + n) * 8, lW1 + c * 8); }
            { const int g = c >> 7, n = c & 127; GLD_LDS16(W2p + ((size_t)(ch * 8 + g) * 128 + n) * 8, lW2 + c * 8); }
        }
        __syncthreads();
        // GEMM1: y[64 x 64dff] = x3 @ W1chunk (A from VGPR)
        f32x4 yacc[2][2] = {};
#pragma unroll
        for (int kk = 0; kk < 4; ++kk) {
            bf16x8 bfr[2];
#pragma unroll
            for (int j = 0; j < 2; ++j)
                bfr[j] = *(const bf16x8*)&lW1[((kk * 4 + ko) * 64 + wc1 + j * 16 + rl) * 8];
#pragma unroll
            for (int i = 0; i < 2; ++i)
#pragma unroll
                for (int j = 0; j < 2; ++j)
                    yacc[i][j] = __builtin_amdgcn_mfma_f32_16x16x32_bf16(afx[i][kk], bfr[j], yacc[i][j], 0, 0, 0);
        }
        // relu+bias -> lY (A-frag layout [dff/8][row][8])
#pragma unroll
        for (int j = 0; j < 2; ++j) {
            const int dff = wc1 + j * 16 + cc;
            const float bb = b1[ch * 64 + dff];
#pragma unroll
            for (int i = 0; i < 2; ++i)
#pragma unroll
                for (int r = 0; r < 4; ++r)
                    lY[((dff >> 3) * 64 + wr + i * 16 + cr + r) * 8 + (dff & 7)] =
                        (bf16_t)fmaxf(yacc[i][j][r] + bb, 0.f);
        }
        __syncthreads();
        // GEMM2: xacc += y @ W2chunk
#pragma unroll
        for (int kk = 0; kk < 2; ++kk) {
            bf16x8 afY[2], bfr2[4];
#pragma unroll
            for (int i = 0; i < 2; ++i)
                afY[i] = *(const bf16x8*)&lY[((kk * 4 + ko) * 64 + wr + i * 16 + rl) * 8];
#pragma unroll
            for (int j = 0; j < 4; ++j)
                bfr2[j] = *(const bf16x8*)&lW2[((kk * 4 + ko) * 128 + wc2 + j * 16 + rl) * 8];
#pragma unroll
            for (int i = 0; i < 2; ++i)
#pragma unroll
                for (int j = 0; j < 4; ++j)
                    xacc[i][j] = __builtin_amdgcn_mfma_f32_16x16x32_bf16(afY[i], bfr2[j], xacc[i][j], 0, 0, 0);
        }
    }
    // epilogue: + b2 + x3 residual (from HBM), LN2, store fp32
#pragma unroll
    for (int j = 0; j < 4; ++j) {
        const int col = wc2 + j * 16 + cc;
        const float bb = b2[col];
#pragma unroll
        for (int i = 0; i < 2; ++i)
#pragma unroll
            for (int r = 0; r < 4; ++r) {
                const int row = wr + i * 16 + cr + r;
                xacc[i][j][r] += bb + (float)x3[(size_t)(row0 + row) * 128 + col];
            }
    }
#pragma unroll
    for (int i = 0; i < 2; ++i)
#pragma unroll
        for (int r = 0; r < 4; ++r) {
            float s1 = 0.f, s2 = 0.f;
#pragma unroll
            for (int j = 0; j < 4; ++j) { const float v = xacc[i][j][r]; s1 += v; s2 += v * v; }
#pragma unroll
            for (int m = 1; m < 16; m <<= 1) {
                s1 += __shfl_xor(s1, m);
                s2 += __shfl_xor(s2, m);
            }
            if (cc == 0) {
                s_s1[wave & 1][wr + i * 16 + cr + r] = s1;
                s_s2[wave & 1][wr + i * 16 + cr + r] = s2;
            }
        }
    __syncthreads();
    if (tid < 64) {
        const float a = s_s1[0][tid] + s_s1[1][tid];
        const float q = s_s2[0][tid] + s_s2[1][tid];
        const float mu = a * (1.f / 128.f);
        s_mu[tid] = mu;
        s_rs[tid] = rsqrtf(q * (1.f / 128.f) - mu * mu + LN_EPS);
    }
    __syncthreads();
#pragma unroll
    for (int j = 0; j < 4; ++j) {
        const int col = wc2 + j * 16 + cc;
        const float gg = gamma[col], bb = beta[col];
#pragma unroll
        for (int i = 0; i < 2; ++i)
#pragma unroll
            for (int r = 0; r < 4; ++r) {
                const int rloc = wr + i * 16 + cr + r;
                out[(size_t)(row0 + rloc) * 128 + col] =
                    (xacc[i][j][r] - s_mu[rloc]) * s_rs[rloc] * gg + bb;
            }
    }
}

// ============ edge build: w = exp(leaky(score)); scatter into CSR slots ============
__global__ __launch_bounds__(256) void edge_build(const float* __restrict__ evals,
                                                  const int* __restrict__ src,
                                                  const int* __restrict__ dst,
                                                  const float* __restrict__ el,
                                                  const float* __restrict__ er,
                                                  const float* __restrict__ ce,
                                                  int* __restrict__ cursor,
                                                  int* __restrict__ csr_src,
                                                  float4* __restrict__ csr_w) {
    const int e = blockIdx.x * 256 + threadIdx.x;
    const int s = src[e], d = dst[e];
    const float ev = evals[e];
    const float4 l = *(const float4*)(el + (size_t)s * 4);
    const float4 r = *(const float4*)(er + (size_t)d * 4);
    const float4 c = *(const float4*)ce;
    float4 w;
    {
        float v;
        v = l.x + r.x + ev * c.x; v = v >= 0.f ? v : SLOPE * v; w.x = __expf(v);
        v = l.y + r.y + ev * c.y; v = v >= 0.f ? v : SLOPE * v; w.y = __expf(v);
        v = l.z + r.z + ev * c.z; v = v >= 0.f ? v : SLOPE * v; w.z = __expf(v);
        v = l.w + r.w + ev * c.w; v = v >= 0.f ? v : SLOPE * v; w.w = __expf(v);
    }
    const int pos = atomicAdd(&cursor[d], 1);
    if (pos < CAP) {
        csr_src[(size_t)d * CAP + pos] = s;
        csr_w[(size_t)d * CAP + pos] = w;
    }
}

// ============ aggregate (fp8 gather): x1 = relu((Σ w*ft[src])/Σw + res + bias) ============
__global__ __launch_bounds__(128) void aggregate_kernel(const unsigned char* __restrict__ ft8,
                                                        const bf16_t* __restrict__ res,
                                                        const int* __restrict__ cursor,
                                                        const int* __restrict__ csr_src,
                                                        const float4* __restrict__ csr_w,
                                                        const float* __restrict__ gat_bias,
                                                        bf16_t* __restrict__ x1) {
    const int n = blockIdx.x, t = threadIdx.x;
    __shared__ int s_src[CAP];
    __shared__ float s_w[CAP][4];
    const int deg = min(cursor[n], CAP);
    const int ht = t >> 5;
    if (t < deg) {
        s_src[t] = csr_src[(size_t)n * CAP + t];
        *(float4*)s_w[t] = csr_w[(size_t)n * CAP + t];
    }
    __syncthreads();
    float4 acc = {0.f, 0.f, 0.f, 0.f};
    float z = 0.f;
    for (int j = 0; j < deg; ++j) {
        const float w = s_w[j][ht];
        z += w;
        const unsigned u = *(const unsigned*)(ft8 + (size_t)s_src[j] * 512 + t * 4);
        const f32x2 lo = e4m3x2_to_f32<false>(u);
        const f32x2 hi = e4m3x2_to_f32<true>(u);
        acc.x += w * lo[0]; acc.y += w * lo[1];
        acc.z += w * hi[0]; acc.w += w * hi[1];
    }
    const float rz = deg > 0 ? 1.f / z : 0.f;
    const uint2 ur = *(const uint2*)(res + (size_t)n * FDIM + t * 4);
    const float4 gb = ((const float4*)gat_bias)[t];
    union { bf16_t b[4]; uint2 u; } pk;
    pk.b[0] = (bf16_t)fmaxf(acc.x * rz + __uint_as_float(ur.x << 16) + gb.x, 0.f);
    pk.b[1] = (bf16_t)fmaxf(acc.y * rz + __uint_as_float(ur.x & 0xFFFF0000u) + gb.y, 0.f);
    pk.b[2] = (bf16_t)fmaxf(acc.z * rz + __uint_as_float(ur.y << 16) + gb.z, 0.f);
    pk.b[3] = (bf16_t)fmaxf(acc.w * rz + __uint_as_float(ur.y & 0xFFFF0000u) + gb.w, 0.f);
    *(uint2*)(x1 + (size_t)n * FDIM + t * 4) = pk.u;
}

extern "C" void kernel_launch(void* const* d_in, const int* in_sizes, int n_in,
                              void* d_out, int out_size, void* d_ws, size_t ws_size,
                              hipStream_t stream) {
    const float* h        = (const float*)d_in[0];
    const float* evals    = (const float*)d_in[1];
    const int*   src      = (const int*)d_in[2];
    const int*   dst      = (const int*)d_in[3];
    const float* W_fc     = (const float*)d_in[5];
    const float* attn_l   = (const float*)d_in[6];
    const float* attn_r   = (const float*)d_in[7];
    const float* W_fe     = (const float*)d_in[8];
    const float* attn_e   = (const float*)d_in[9];
    const float* W_res    = (const float*)d_in[10];
    const float* gat_bias = (const float*)d_in[11];
    const float* W_mha    = (const float*)d_in[12];
    const float* b_mha    = (const float*)d_in[13];
    const float* n1_g     = (const float*)d_in[14];
    const float* n1_b     = (const float*)d_in[15];
    const float* n2_g     = (const float*)d_in[16];
    const float* n2_b     = (const float*)d_in[17];
    const float* W1       = (const float*)d_in[18];
    const float* b1       = (const float*)d_in[19];
    const float* W2       = (const float*)d_in[20];
    const float* b2       = (const float*)d_in[21];

    char* ws = (char*)d_ws;
    unsigned char* ft8 = (unsigned char*)(ws + 0);   // 16MB  N x 512 fp8
    bf16_t* res     = (bf16_t*)(ws + 16777216ull);   // 32MB  N x 512
    bf16_t* x1      = (bf16_t*)(ws + 50331648ull);   // 32MB  N x 512
    float4* csr_w   = (float4*)(ws + 83886080ull);   // 32MB  N x CAP x 16B
    int*    csr_src = (int*)   (ws + 117440512ull);  // 8MB   N x CAP
    bf16_t* x3b     = (bf16_t*)(ws + 125829120ull);  // 8MB   N x 128
    bf16_t* hb      = (bf16_t*)(ws + 134217728ull);  // 8MB   N x 128
    bf16_t* Wfc_p   = (bf16_t*)(ws + 142606336ull);  // 128KB
    bf16_t* Wres_p  = (bf16_t*)(ws + 142737408ull);  // 128KB
    bf16_t* Wmha_p  = (bf16_t*)(ws + 142868480ull);  // 128KB
    bf16_t* W1_p    = (bf16_t*)(ws + 142999552ull);  // 512KB
    bf16_t* W2_p    = (bf16_t*)(ws + 143523840ull);  // 512KB
    float*  el      = (float*) (ws + 144048128ull);  // 512KB
    float*  er      = (float*) (ws + 144572416ull);  // 512KB
    float*  ce      = (float*) (ws + 145096704ull);  // 16B
    int*    cursor  = (int*)   (ws + 145096768ull);  // 128KB

    if (ws_size < 146000000ull) return;

    (void)hipMemsetAsync(cursor, 0, 131072, stream);

    prep_kernel<<<4449, 256, 0, stream>>>(h, hb, W_fc, Wfc_p, W_res, Wres_p,
                                          W_mha, Wmha_p, W1, W1_p, W2, W2_p,
                                          W_fe, attn_e, ce);
    gemm_ft<<<dim3(4, 256), 256, 0, stream>>>(hb, Wfc_p, attn_l, attn_r, ft8, el, er);
    gemm_mfma<<<dim3(4, 256), 256, 0, stream>>>(hb, Wres_p, res, N_NODES, FDIM, 128);
    edge_build<<<E_EDGES / 256, 256, 0, stream>>>(evals, src, dst, el, er, ce, cursor, csr_src, csr_w);
    aggregate_kernel<<<N_NODES, 128, 0, stream>>>(ft8, res, cursor, csr_src, csr_w, gat_bias, x1);
    gemm_mha_ln<<<256, 256, 0, stream>>>(x1, Wmha_p, b_mha, h, n1_g, n1_b, x3b);
    ffn_fused<<<512, 256, 0, stream>>>(x3b, W1_p, b1, W2_p, b2, n2_g, n2_b, (float*)d_out);
}